// Round 5
// baseline (483.841 us; speedup 1.0000x reference)
//
#include <hip/hip_runtime.h>

#define B_ 512
#define F_ 128
#define D_ 1024
#define EPS_ 1e-5f

typedef float f32x4 __attribute__((ext_vector_type(4)));
typedef __bf16 bf16x4 __attribute__((ext_vector_type(4)));
typedef __bf16 bf16x8 __attribute__((ext_vector_type(8)));

// ---- attn2 -> [LN2 recompute] + residual-with-lin + LN3 -> fp32 out ------
__global__ __launch_bounds__(256) void k_final(
    const float* __restrict__ A2, const float* __restrict__ X2,
    const float* __restrict__ g2, const float* __restrict__ b2,
    const float* __restrict__ g3, const float* __restrict__ b3,
    float* __restrict__ out) {
  int row = blockIdx.x, t = threadIdx.x;
  f32x4 a = *(const f32x4*)(A2 + (size_t)row * D_ + t * 4);
  float s = a[0] + a[1] + a[2] + a[3];
  float ss = a[0] * a[0] + a[1] * a[1] + a[2] * a[2] + a[3] * a[3];
#pragma unroll
  for (int o = 32; o > 0; o >>= 1) { s += __shfl_xor(s, o); ss += __shfl_xor(ss, o); }
  __shared__ float ws[4][2];
  int w = t >> 6;
  if ((t & 63) == 0) { ws[w][0] = s; ws[w][1] = ss; }
  __syncthreads();
  s = ws[0][0] + ws[1][0] + ws[2][0] + ws[3][0];
  ss = ws[0][1] + ws[1][1] + ws[2][1] + ws[3][1];
  float mu2 = s * (1.0f / D_);
  float var2 = ss * (1.0f / D_) - mu2 * mu2;
  float rs2 = rsqrtf(var2 + EPS_);
  f32x4 g2v = *(const f32x4*)(g2 + t * 4);
  f32x4 b2v = *(const f32x4*)(b2 + t * 4);
  f32x4 lin = *(const f32x4*)(X2 + (size_t)row * D_ + t * 4);
  f32x4 v;
#pragma unroll
  for (int i = 0; i < 4; i++) {
    float attno = (a[i] - mu2) * rs2 * g2v[i] + b2v[i];
    v[i] = attno + lin[i];
  }
  // ---- LN3 ----
  s = v[0] + v[1] + v[2] + v[3];
  ss = v[0] * v[0] + v[1] * v[1] + v[2] * v[2] + v[3] * v[3];
#pragma unroll
  for (int o = 32; o > 0; o >>= 1) { s += __shfl_xor(s, o); ss += __shfl_xor(ss, o); }
  __syncthreads();   // ws re-use hazard
  if ((t & 63) == 0) { ws[w][0] = s; ws[w][1] = ss; }
  __syncthreads();
  s = ws[0][0] + ws[1][0] + ws[2][0] + ws[3][0];
  ss = ws[0][1] + ws[1][1] + ws[2][1] + ws[3][1];
  float mu = s * (1.0f / D_);
  float var = ss * (1.0f / D_) - mu * mu;
  float rs = rsqrtf(var + EPS_);
  f32x4 gg = *(const f32x4*)(g3 + t * 4);
  f32x4 bb = *(const f32x4*)(b3 + t * 4);
  f32x4 o4;
#pragma unroll
  for (int i = 0; i < 4; i++) o4[i] = (v[i] - mu) * rs * gg[i] + bb[i];
  *(f32x4*)(out + (size_t)row * D_ + t * 4) = o4;
}

// ---- weight prep: fp32 -> bf16 (job 1 transposes). z=5: text LayerNorm. ---
__global__ __launch_bounds__(256) void k_wprep(
    const float* __restrict__ w0, const float* __restrict__ w1,
    const float* __restrict__ w2, const float* __restrict__ w3,
    const float* __restrict__ w4, __bf16* __restrict__ o0,
    __bf16* __restrict__ o1, __bf16* __restrict__ o2,
    __bf16* __restrict__ o3, __bf16* __restrict__ o4p,
    const float* __restrict__ text, const float* __restrict__ g1,
    const float* __restrict__ b1, __bf16* __restrict__ Yh,
    __bf16* __restrict__ Yl) {
  int z = blockIdx.z;
  int t = threadIdx.x;
  if (z == 5) {
    // ---- fused text LayerNorm (1024 blocks in z-slice, 512 used) ----
    int row = blockIdx.y * 32 + blockIdx.x;
    if (row >= B_) return;
    f32x4 xv = *(const f32x4*)(text + (size_t)row * D_ + t * 4);
    float s = xv[0] + xv[1] + xv[2] + xv[3];
    float ss = xv[0]*xv[0] + xv[1]*xv[1] + xv[2]*xv[2] + xv[3]*xv[3];
#pragma unroll
    for (int o = 32; o > 0; o >>= 1) { s += __shfl_xor(s, o); ss += __shfl_xor(ss, o); }
    __shared__ float ws[4][2];
    int w = t >> 6;
    if ((t & 63) == 0) { ws[w][0] = s; ws[w][1] = ss; }
    __syncthreads();
    s = ws[0][0] + ws[1][0] + ws[2][0] + ws[3][0];
    ss = ws[0][1] + ws[1][1] + ws[2][1] + ws[3][1];
    float mu = s * (1.0f / D_);
    float var = ss * (1.0f / D_) - mu * mu;
    float rs = rsqrtf(var + EPS_);
    f32x4 gg = *(const f32x4*)(g1 + t * 4);
    f32x4 bb = *(const f32x4*)(b1 + t * 4);
    bf16x4 h4, l4;
#pragma unroll
    for (int i = 0; i < 4; i++) {
      float o = (xv[i] - mu) * rs * gg[i] + bb[i];
      h4[i] = (__bf16)o;
      l4[i] = (__bf16)(o - (float)h4[i]);
    }
    *(bf16x4*)(Yh + (size_t)row * D_ + t * 4) = h4;
    *(bf16x4*)(Yl + (size_t)row * D_ + t * 4) = l4;
    return;
  }
  const float* src = (z == 0) ? w0 : (z == 1) ? w1 : (z == 2) ? w2 : (z == 3) ? w3 : w4;
  __bf16* dst = (z == 0) ? o0 : (z == 1) ? o1 : (z == 2) ? o2 : (z == 3) ? o3 : o4p;
  if (z != 1) {
    int row = blockIdx.y * 32 + (t >> 3);
    int col = blockIdx.x * 32 + (t & 7) * 4;
    f32x4 v = *(const f32x4*)(src + (size_t)row * D_ + col);
    bf16x4 o;
    o[0] = (__bf16)v[0]; o[1] = (__bf16)v[1]; o[2] = (__bf16)v[2]; o[3] = (__bf16)v[3];
    *(bf16x4*)(dst + (size_t)row * D_ + col) = o;
  } else {
    __shared__ float tile[32][33];
    int ti = blockIdx.y, tj = blockIdx.x;
    int c = t & 31, r0 = t >> 5;
#pragma unroll
    for (int i = 0; i < 4; i++) {
      int r = r0 + i * 8;
      tile[r][c] = src[(size_t)(ti * 32 + r) * D_ + tj * 32 + c];
    }
    __syncthreads();
#pragma unroll
    for (int i = 0; i < 4; i++) {
      int r = r0 + i * 8;
      dst[(size_t)(tj * 32 + r) * D_ + ti * 32 + c] = (__bf16)tile[c][r];
    }
  }
}

// ---- GEMM: C[M,N] = (Ah+Al)[M,K] @ W[N,K]^T + bias. 32x32 tile per block. --
// Split-K x8: 512 threads = 8 waves, wave w owns K-slice [w*K/8, (w+1)*K/8).
// Frag layout: A/B row = lane&15, k = (lane>>4)*8+j ; C/D col = lane&15, row = quad*4+reg
template <int OUT>
__global__ __launch_bounds__(512) void k_gemm32(
    const __bf16* __restrict__ Ah, const __bf16* __restrict__ Al,
    const __bf16* __restrict__ W, const float* __restrict__ bias,
    float* __restrict__ Cf, __bf16* __restrict__ Ch, __bf16* __restrict__ Cl,
    int N, int K) {
  int t = threadIdx.x;
  int lane = t & 63, wv = t >> 6;      // 8 waves
  int r = lane & 15, quad = lane >> 4;
  int tn = blockIdx.x, tm = blockIdx.y;
  int kw = K >> 3;                     // 128 per wave
  const __bf16* pah0 = Ah + (size_t)(tm * 32 + r) * K + wv * kw + quad * 8;
  const __bf16* pah1 = pah0 + (size_t)16 * K;
  const __bf16* pal0 = Al + (size_t)(tm * 32 + r) * K + wv * kw + quad * 8;
  const __bf16* pal1 = pal0 + (size_t)16 * K;
  const __bf16* pw0 = W + (size_t)(tn * 32 + r) * K + wv * kw + quad * 8;
  const __bf16* pw1 = pw0 + (size_t)16 * K;
  f32x4 acc00 = {0,0,0,0}, acc01 = {0,0,0,0}, acc10 = {0,0,0,0}, acc11 = {0,0,0,0};
  bf16x8 ah0 = *(const bf16x8*)pah0, ah1 = *(const bf16x8*)pah1;
  bf16x8 al0 = *(const bf16x8*)pal0, al1 = *(const bf16x8*)pal1;
  bf16x8 w0v = *(const bf16x8*)pw0, w1v = *(const bf16x8*)pw1;
  for (int k0 = 0; k0 < kw; k0 += 32) {
    int kn = (k0 + 32 < kw) ? (k0 + 32) : 0;  // dummy refetch on last iter
    bf16x8 nah0 = *(const bf16x8*)(pah0 + kn);
    bf16x8 nah1 = *(const bf16x8*)(pah1 + kn);
    bf16x8 nal0 = *(const bf16x8*)(pal0 + kn);
    bf16x8 nal1 = *(const bf16x8*)(pal1 + kn);
    bf16x8 nw0 = *(const bf16x8*)(pw0 + kn);
    bf16x8 nw1 = *(const bf16x8*)(pw1 + kn);
    acc00 = __builtin_amdgcn_mfma_f32_16x16x32_bf16(ah0, w0v, acc00, 0, 0, 0);
    acc01 = __builtin_amdgcn_mfma_f32_16x16x32_bf16(ah0, w1v, acc01, 0, 0, 0);
    acc10 = __builtin_amdgcn_mfma_f32_16x16x32_bf16(ah1, w0v, acc10, 0, 0, 0);
    acc11 = __builtin_amdgcn_mfma_f32_16x16x32_bf16(ah1, w1v, acc11, 0, 0, 0);
    acc00 = __builtin_amdgcn_mfma_f32_16x16x32_bf16(al0, w0v, acc00, 0, 0, 0);
    acc01 = __builtin_amdgcn_mfma_f32_16x16x32_bf16(al0, w1v, acc01, 0, 0, 0);
    acc10 = __builtin_amdgcn_mfma_f32_16x16x32_bf16(al1, w0v, acc10, 0, 0, 0);
    acc11 = __builtin_amdgcn_mfma_f32_16x16x32_bf16(al1, w1v, acc11, 0, 0, 0);
    ah0 = nah0; ah1 = nah1; al0 = nal0; al1 = nal1; w0v = nw0; w1v = nw1;
  }
  // ---- cross-wave split-K reduction via LDS (pad 17 -> conflict-light) ----
  __shared__ float red[8][64][17];
  *(f32x4*)(&red[wv][lane][0])  = acc00;
  *(f32x4*)(&red[wv][lane][4])  = acc01;
  *(f32x4*)(&red[wv][lane][8])  = acc10;
  *(f32x4*)(&red[wv][lane][12]) = acc11;
  __syncthreads();
  // 1024 outputs, 512 threads -> 2 each. j in [0,16): a=j>>2 (acc), i=j&3.
  int re = lane & 15, qe = lane >> 4;
#pragma unroll
  for (int u = 0; u < 2; u++) {
    int j = (t >> 6) * 2 + u;
    int a = j >> 2, i = j & 3;
    float val = 0.0f;
#pragma unroll
    for (int ww = 0; ww < 8; ww++) val += red[ww][lane][j];
    int row = tm * 32 + qe * 4 + i + ((a >> 1) << 4);
    int col = tn * 32 + re + ((a & 1) << 4);
    if (bias) val += bias[col];
    size_t o = (size_t)row * N + col;
    if (OUT == 0) {
      Cf[o] = val;
    } else {
      __bf16 h = (__bf16)val;
      Ch[o] = h;
      Cl[o] = (__bf16)(val - (float)h);
    }
  }
}

// ---- lin GEMM with LN2 fused in the prologue ------------------------------
// C[M,N] = LN2(A)[M,K] @ W[N,K]^T + bias, A fp32. Each block's waves jointly
// hold the full K extent of its 32 A-rows, so per-row LN stats are a block-
// local LDS reduction; rows are normalized in-register, converted to bf16
// hi/lo fragments, then the standard split-K MFMA schedule runs unchanged.
__global__ __launch_bounds__(512) void k_gemm32ln(
    const float* __restrict__ Af, const __bf16* __restrict__ W,
    const float* __restrict__ bias, const float* __restrict__ g2,
    const float* __restrict__ b2, float* __restrict__ Cf, int N, int K) {
  int t = threadIdx.x;
  int lane = t & 63, wv = t >> 6;      // 8 waves
  int r = lane & 15, quad = lane >> 4;
  int tn = blockIdx.x, tm = blockIdx.y;
  int kw = K >> 3;                     // 128 per wave
  int kbase = wv * kw + quad * 8;
  const float* pa0 = Af + (size_t)(tm * 32 + r) * K + kbase;
  const float* pa1 = pa0 + (size_t)16 * K;
  // ---- pass 1: per-row partial sums over this thread's 32 elems/row ----
  float s0 = 0.f, q0 = 0.f, s1 = 0.f, q1 = 0.f;
#pragma unroll
  for (int c = 0; c < 4; c++) {
    f32x4 xa = *(const f32x4*)(pa0 + c * 32);
    f32x4 xb = *(const f32x4*)(pa0 + c * 32 + 4);
    f32x4 ya = *(const f32x4*)(pa1 + c * 32);
    f32x4 yb = *(const f32x4*)(pa1 + c * 32 + 4);
#pragma unroll
    for (int j = 0; j < 4; j++) {
      s0 += xa[j] + xb[j];
      q0 += xa[j] * xa[j] + xb[j] * xb[j];
      s1 += ya[j] + yb[j];
      q1 += ya[j] * ya[j] + yb[j] * yb[j];
    }
  }
  __shared__ float red2[2][16][2][32];   // [half][r][stat][wv*4+quad]
  __shared__ float stat_s[2][32];        // [stat][tile row]
  int cid = wv * 4 + quad;
  red2[0][r][0][cid] = s0; red2[0][r][1][cid] = q0;
  red2[1][r][0][cid] = s1; red2[1][r][1][cid] = q1;
  __syncthreads();
  if (t < 64) {
    int rowid = t & 31, st = t >> 5;
    int h = rowid >> 4, rr = rowid & 15;
    float acc = 0.f;
#pragma unroll
    for (int c = 0; c < 32; c++) acc += red2[h][rr][st][c];
    stat_s[st][rowid] = acc;
  }
  __syncthreads();
  float mu0 = stat_s[0][r] * (1.0f / D_);
  float rs0 = rsqrtf(stat_s[1][r] * (1.0f / D_) - mu0 * mu0 + EPS_);
  float mu1 = stat_s[0][r + 16] * (1.0f / D_);
  float rs1 = rsqrtf(stat_s[1][r + 16] * (1.0f / D_) - mu1 * mu1 + EPS_);
  // ---- pass 2: reload, normalize, convert to bf16 hi/lo fragments ----
  bf16x8 aH[2][4], aL[2][4];
#pragma unroll
  for (int c = 0; c < 4; c++) {
    f32x4 ga = *(const f32x4*)(g2 + kbase + c * 32);
    f32x4 gb = *(const f32x4*)(g2 + kbase + c * 32 + 4);
    f32x4 ba = *(const f32x4*)(b2 + kbase + c * 32);
    f32x4 bb = *(const f32x4*)(b2 + kbase + c * 32 + 4);
    f32x4 xa = *(const f32x4*)(pa0 + c * 32);
    f32x4 xb = *(const f32x4*)(pa0 + c * 32 + 4);
    f32x4 ya = *(const f32x4*)(pa1 + c * 32);
    f32x4 yb = *(const f32x4*)(pa1 + c * 32 + 4);
    bf16x8 h0v, l0v, h1v, l1v;
#pragma unroll
    for (int j = 0; j < 4; j++) {
      float o = (xa[j] - mu0) * rs0 * ga[j] + ba[j];
      __bf16 hh = (__bf16)o; h0v[j] = hh; l0v[j] = (__bf16)(o - (float)hh);
      o = (xb[j] - mu0) * rs0 * gb[j] + bb[j];
      hh = (__bf16)o; h0v[4 + j] = hh; l0v[4 + j] = (__bf16)(o - (float)hh);
      o = (ya[j] - mu1) * rs1 * ga[j] + ba[j];
      hh = (__bf16)o; h1v[j] = hh; l1v[j] = (__bf16)(o - (float)hh);
      o = (yb[j] - mu1) * rs1 * gb[j] + bb[j];
      hh = (__bf16)o; h1v[4 + j] = hh; l1v[4 + j] = (__bf16)(o - (float)hh);
    }
    aH[0][c] = h0v; aL[0][c] = l0v; aH[1][c] = h1v; aL[1][c] = l1v;
  }
  // ---- MFMA over 4 chunks, W prefetched ----
  const __bf16* pw0 = W + (size_t)(tn * 32 + r) * K + kbase;
  const __bf16* pw1 = pw0 + (size_t)16 * K;
  f32x4 acc00 = {0,0,0,0}, acc01 = {0,0,0,0}, acc10 = {0,0,0,0}, acc11 = {0,0,0,0};
  bf16x8 w0v = *(const bf16x8*)pw0, w1v = *(const bf16x8*)pw1;
#pragma unroll
  for (int c = 0; c < 4; c++) {
    int nc = (c < 3) ? (c + 1) * 32 : 0;
    bf16x8 nw0 = *(const bf16x8*)(pw0 + nc);
    bf16x8 nw1 = *(const bf16x8*)(pw1 + nc);
    acc00 = __builtin_amdgcn_mfma_f32_16x16x32_bf16(aH[0][c], w0v, acc00, 0, 0, 0);
    acc01 = __builtin_amdgcn_mfma_f32_16x16x32_bf16(aH[0][c], w1v, acc01, 0, 0, 0);
    acc10 = __builtin_amdgcn_mfma_f32_16x16x32_bf16(aH[1][c], w0v, acc10, 0, 0, 0);
    acc11 = __builtin_amdgcn_mfma_f32_16x16x32_bf16(aH[1][c], w1v, acc11, 0, 0, 0);
    acc00 = __builtin_amdgcn_mfma_f32_16x16x32_bf16(aL[0][c], w0v, acc00, 0, 0, 0);
    acc01 = __builtin_amdgcn_mfma_f32_16x16x32_bf16(aL[0][c], w1v, acc01, 0, 0, 0);
    acc10 = __builtin_amdgcn_mfma_f32_16x16x32_bf16(aL[1][c], w0v, acc10, 0, 0, 0);
    acc11 = __builtin_amdgcn_mfma_f32_16x16x32_bf16(aL[1][c], w1v, acc11, 0, 0, 0);
    w0v = nw0; w1v = nw1;
  }
  // ---- cross-wave split-K reduction (same as k_gemm32) ----
  __shared__ float red[8][64][17];
  *(f32x4*)(&red[wv][lane][0])  = acc00;
  *(f32x4*)(&red[wv][lane][4])  = acc01;
  *(f32x4*)(&red[wv][lane][8])  = acc10;
  *(f32x4*)(&red[wv][lane][12]) = acc11;
  __syncthreads();
  int re = lane & 15, qe = lane >> 4;
#pragma unroll
  for (int u = 0; u < 2; u++) {
    int j = (t >> 6) * 2 + u;
    int a = j >> 2, i = j & 3;
    float val = 0.0f;
#pragma unroll
    for (int ww = 0; ww < 8; ww++) val += red[ww][lane][j];
    int row = tm * 32 + qe * 4 + i + ((a >> 1) << 4);
    int col = tn * 32 + re + ((a & 1) << 4);
    val += bias[col];
    Cf[(size_t)row * N + col] = val;
  }
}

// ---------------- fused flash-style attention over video -------------------
// One block (16 waves) per b. Wave w owns rows [w*8, w*8+8); per-lane cols
// lane*4 + i*256. Per-b prep (sum_gq, dot_bq, qkb, gq) fused into the
// prologue as per-wave shuffle reductions. PV accumulator stays column-local
// in registers -> NO barriers in the main loop. Per-wave online softmax
// (m,S,C,O); single flash-merge at the end.
__global__ __launch_bounds__(1024) void k_attn(
    const float* __restrict__ video, const float* __restrict__ q2,
    const __bf16* __restrict__ qh, const __bf16* __restrict__ ql,
    const float* __restrict__ g, const float* __restrict__ bv,
    const float* __restrict__ kb, __bf16* __restrict__ ctxh,
    __bf16* __restrict__ ctxl) {
  __shared__ float Xc[16][1032];     // per-wave scaled O partials (padded)
  __shared__ float mSC[16][4];       // m_w, S_w, C_w per wave
  int b = blockIdx.x, t = threadIdx.x;
  int w = t >> 6, lane = t & 63;
  // issue first video frame loads immediately (critical HBM path)
  const float* vbase = video + ((size_t)b * F_ + w * 8) * D_ + lane * 4;
  f32x4 vA[4], vB[4];
#pragma unroll
  for (int i = 0; i < 4; i++) vA[i] = *(const f32x4*)(vbase + i * 256);
  // ---- fused per-b prep: gq (regs), sum_gq, dot_bq, qkb (wave reduce) ----
  const float* q2p = q2 + (size_t)b * D_ + lane * 4;
  const float* gp = g + lane * 4;
  const float* bp = bv + lane * 4;
  const float* kp = kb + lane * 4;
  const __bf16* qhp = qh + (size_t)b * D_ + lane * 4;
  const __bf16* qlp = ql + (size_t)b * D_ + lane * 4;
  f32x4 gqr[4];
  float s1 = 0.f, s2 = 0.f, s3 = 0.f;
#pragma unroll
  for (int i = 0; i < 4; i++) {
    f32x4 qv = *(const f32x4*)(q2p + i * 256);
    f32x4 g4 = *(const f32x4*)(gp + i * 256);
    f32x4 b4 = *(const f32x4*)(bp + i * 256);
    f32x4 k4 = *(const f32x4*)(kp + i * 256);
    bf16x4 h4 = *(const bf16x4*)(qhp + i * 256);
    bf16x4 l4 = *(const bf16x4*)(qlp + i * 256);
#pragma unroll
    for (int j = 0; j < 4; j++) {
      float gq = g4[j] * qv[j];
      gqr[i][j] = gq;
      s1 += gq;
      s2 += b4[j] * qv[j];
      s3 += k4[j] * ((float)h4[j] + (float)l4[j]);
    }
  }
#pragma unroll
  for (int o = 32; o > 0; o >>= 1) {
    s1 += __shfl_xor(s1, o); s2 += __shfl_xor(s2, o); s3 += __shfl_xor(s3, o);
  }
  float sgq = s1, dbq = s2, qk = s3;
  f32x4 O[4];
#pragma unroll
  for (int i = 0; i < 4; i++) O[i] = (f32x4){0.f, 0.f, 0.f, 0.f};
  float m_run = -1e30f, S = 0.0f, Cc = 0.0f;
  for (int f = 0; f < 8; f++) {
    if (f < 7) {
      const float* nb = vbase + (size_t)(f + 1) * D_;
#pragma unroll
      for (int i = 0; i < 4; i++) vB[i] = *(const f32x4*)(nb + i * 256);
    }
    float sx = 0.f, sxx = 0.f, sxg = 0.f;
#pragma unroll
    for (int i = 0; i < 4; i++) {
      f32x4 v = vA[i], gg = gqr[i];
#pragma unroll
      for (int j = 0; j < 4; j++) {
        sx += v[j];
        sxx += v[j] * v[j];
        sxg += v[j] * gg[j];
      }
    }
#pragma unroll
    for (int o = 32; o > 0; o >>= 1) {
      sx += __shfl_xor(sx, o);
      sxx += __shfl_xor(sxx, o);
      sxg += __shfl_xor(sxg, o);
    }
    float mu = sx * (1.0f / D_);
    float var = sxx * (1.0f / D_) - mu * mu;
    float rs = rsqrtf(var + EPS_);
    float l = (rs * (sxg - mu * sgq) + dbq + qk) * 0.03125f;
    float m_new = fmaxf(m_run, l);
    float alpha = __expf(m_run - m_new);
    float e = __expf(l - m_new);
    float af = e * rs;
    S = S * alpha + e;
    Cc = Cc * alpha + af * mu;
#pragma unroll
    for (int i = 0; i < 4; i++) {
#pragma unroll
      for (int j = 0; j < 4; j++) O[i][j] = O[i][j] * alpha + af * vA[i][j];
    }
    m_run = m_new;
#pragma unroll
    for (int i = 0; i < 4; i++) vA[i] = vB[i];
  }
  // ---- flash merge of 16 per-wave states ----
  if (lane == 0) { mSC[w][0] = m_run; mSC[w][1] = S; mSC[w][2] = Cc; }
  __syncthreads();
  float mstar = -1e30f;
#pragma unroll
  for (int i = 0; i < 16; i++) mstar = fmaxf(mstar, mSC[i][0]);
  float myscale = __expf(m_run - mstar);
#pragma unroll
  for (int i = 0; i < 4; i++) {
    f32x4 o4;
#pragma unroll
    for (int j = 0; j < 4; j++) o4[j] = O[i][j] * myscale;
    *(f32x4*)(&Xc[w][lane * 4 + i * 256]) = o4;
  }
  float Sstar = 0.f, Cstar = 0.f;
#pragma unroll
  for (int i = 0; i < 16; i++) {
    float e = __expf(mSC[i][0] - mstar);
    Sstar += mSC[i][1] * e;
    Cstar += mSC[i][2] * e;
  }
  __syncthreads();
  float Osum = 0.f;
#pragma unroll
  for (int i = 0; i < 16; i++) Osum += Xc[i][t];
  float inv = 1.0f / Sstar;
  float v = g[t] * ((Osum - Cstar) * inv) + bv[t];
  __bf16 h = (__bf16)v;
  ctxh[(size_t)b * D_ + t] = h;
  ctxl[(size_t)b * D_ + t] = (__bf16)(v - (float)h);
}

extern "C" void kernel_launch(void* const* d_in, const int* in_sizes, int n_in,
                              void* d_out, int out_size, void* d_ws, size_t ws_size,
                              hipStream_t stream) {
  (void)in_sizes; (void)n_in; (void)out_size; (void)ws_size;
  const float* text = (const float*)d_in[0];
  const float* video = (const float*)d_in[1];
  const float* q_w = (const float*)d_in[2];
  const float* k_w = (const float*)d_in[3];
  const float* v_w = (const float*)d_in[4];
  const float* out_w = (const float*)d_in[5];
  const float* lin_w = (const float*)d_in[6];
  const float* q_b = (const float*)d_in[7];
  const float* k_b = (const float*)d_in[8];
  const float* v_b = (const float*)d_in[9];
  const float* out_b = (const float*)d_in[10];
  const float* lin_b = (const float*)d_in[11];
  const float* ln1_g = (const float*)d_in[12];
  const float* ln1_b = (const float*)d_in[13];
  const float* ln2_g = (const float*)d_in[14];
  const float* ln2_b = (const float*)d_in[15];
  const float* ln3_g = (const float*)d_in[16];
  const float* ln3_b = (const float*)d_in[17];
  float* out = (float*)d_out;

  const size_t BD = (size_t)B_ * D_;   // 524288
  const size_t DD = (size_t)D_ * D_;   // 1048576
  float* f = (float*)d_ws;
  float* slotF1 = f;            // BD fp32 (q2, attn2)
  float* slotF2 = f + BD;       // BD fp32 (lin)
  float* scratch = f + 2 * BD;
  __bf16* P1h = (__bf16*)(scratch + 4 * B_);  // plane pair 1 (t_ln, ctx)
  __bf16* P1l = P1h + BD;
  __bf16* P2h = P1h + 2 * BD;                 // plane pair 2 (qv, attn1)
  __bf16* P2l = P1h + 3 * BD;
  __bf16* Wq = P1h + 6 * BD;
  __bf16* WkT = Wq + DD;
  __bf16* Wv = Wq + 2 * DD;
  __bf16* Wo = Wq + 3 * DD;
  __bf16* Wl = Wq + 4 * DD;
  // total ws use: ~24.5 MB

  dim3 gemm_grid(D_ / 32, B_ / 32);  // (32, 16)

  // weights -> bf16 (+ k_w transpose) and text LayerNorm, one dispatch
  k_wprep<<<dim3(32, 32, 6), 256, 0, stream>>>(q_w, k_w, v_w, out_w, lin_w,
                                               Wq, WkT, Wv, Wo, Wl,
                                               text, ln1_g, ln1_b, P1h, P1l);
  // q path
  k_gemm32<1><<<gemm_grid, 512, 0, stream>>>(P1h, P1l, Wq, q_b, nullptr, P2h, P2l, D_, D_);   // qv
  k_gemm32<0><<<gemm_grid, 512, 0, stream>>>(P2h, P2l, WkT, nullptr, slotF1, nullptr, nullptr, D_, D_); // q2
  // fused attention (prep_q folded in): video read once; ctx -> P1 planes
  k_attn<<<B_, 1024, 0, stream>>>(video, slotF1, P2h, P2l,
                                  ln1_g, ln1_b, k_b, P1h, P1l);
  // output projections + norms
  k_gemm32<1><<<gemm_grid, 512, 0, stream>>>(P1h, P1l, Wv, v_b, nullptr, P2h, P2l, D_, D_);   // attn1
  k_gemm32<0><<<gemm_grid, 512, 0, stream>>>(P2h, P2l, Wo, out_b, slotF1, nullptr, nullptr, D_, D_); // attn2
  // lin GEMM with LN2 fused (reads attn2 fp32 directly)
  k_gemm32ln<<<gemm_grid, 512, 0, stream>>>(slotF1, Wl, lin_b, ln2_g, ln2_b,
                                            slotF2, D_, D_);                   // lin
  // final: recompute LN2(attn2) + residual + LN3
  k_final<<<B_, 256, 0, stream>>>(slotF1, slotF2, ln2_g, ln2_b, ln3_g, ln3_b, out);
}

// Round 7
// 476.276 us; speedup vs baseline: 1.0159x; 1.0159x over previous
//
#include <hip/hip_runtime.h>

#define B_ 512
#define F_ 128
#define D_ 1024
#define EPS_ 1e-5f

typedef float f32x4 __attribute__((ext_vector_type(4)));
typedef __bf16 bf16x4 __attribute__((ext_vector_type(4)));
typedef __bf16 bf16x8 __attribute__((ext_vector_type(8)));

// ---- LayerNorm rows of D=1024, fp32 in; OUT=0: fp32 out, OUT=1: bf16 hi/lo
template <int OUT>
__global__ __launch_bounds__(256) void k_ln(
    const float* __restrict__ X, const float* __restrict__ g,
    const float* __restrict__ bv, float* __restrict__ Yf,
    __bf16* __restrict__ Yh, __bf16* __restrict__ Yl) {
  int row = blockIdx.x, t = threadIdx.x;
  f32x4 xv = *(const f32x4*)(X + (size_t)row * D_ + t * 4);
  float s = xv[0] + xv[1] + xv[2] + xv[3];
  float ss = xv[0] * xv[0] + xv[1] * xv[1] + xv[2] * xv[2] + xv[3] * xv[3];
#pragma unroll
  for (int o = 32; o > 0; o >>= 1) { s += __shfl_xor(s, o); ss += __shfl_xor(ss, o); }
  __shared__ float ws[4][2];
  int w = t >> 6;
  if ((t & 63) == 0) { ws[w][0] = s; ws[w][1] = ss; }
  __syncthreads();
  s = ws[0][0] + ws[1][0] + ws[2][0] + ws[3][0];
  ss = ws[0][1] + ws[1][1] + ws[2][1] + ws[3][1];
  float mu = s * (1.0f / D_);
  float var = ss * (1.0f / D_) - mu * mu;
  float rs = rsqrtf(var + EPS_);
  f32x4 gg = *(const f32x4*)(g + t * 4);
  f32x4 bb = *(const f32x4*)(bv + t * 4);
  f32x4 o4;
#pragma unroll
  for (int i = 0; i < 4; i++) o4[i] = (xv[i] - mu) * rs * gg[i] + bb[i];
  if (OUT == 0) {
    *(f32x4*)(Yf + (size_t)row * D_ + t * 4) = o4;
  } else {
    bf16x4 h4, l4;
#pragma unroll
    for (int i = 0; i < 4; i++) {
      h4[i] = (__bf16)o4[i];
      l4[i] = (__bf16)(o4[i] - (float)h4[i]);
    }
    *(bf16x4*)(Yh + (size_t)row * D_ + t * 4) = h4;
    *(bf16x4*)(Yl + (size_t)row * D_ + t * 4) = l4;
  }
}

// ---- residual add + LayerNorm -> fp32 output (X1 = hi/lo planes, X2 fp32) -
__global__ __launch_bounds__(256) void k_final(
    const __bf16* __restrict__ X1h, const __bf16* __restrict__ X1l,
    const float* __restrict__ X2, const float* __restrict__ g,
    const float* __restrict__ bv, float* __restrict__ out) {
  int row = blockIdx.x, t = threadIdx.x;
  bf16x4 h4 = *(const bf16x4*)(X1h + (size_t)row * D_ + t * 4);
  bf16x4 l4 = *(const bf16x4*)(X1l + (size_t)row * D_ + t * 4);
  f32x4 b = *(const f32x4*)(X2 + (size_t)row * D_ + t * 4);
  f32x4 v;
#pragma unroll
  for (int i = 0; i < 4; i++) v[i] = (float)h4[i] + (float)l4[i] + b[i];
  float s = v[0] + v[1] + v[2] + v[3];
  float ss = v[0] * v[0] + v[1] * v[1] + v[2] * v[2] + v[3] * v[3];
#pragma unroll
  for (int o = 32; o > 0; o >>= 1) { s += __shfl_xor(s, o); ss += __shfl_xor(ss, o); }
  __shared__ float ws[4][2];
  int w = t >> 6;
  if ((t & 63) == 0) { ws[w][0] = s; ws[w][1] = ss; }
  __syncthreads();
  s = ws[0][0] + ws[1][0] + ws[2][0] + ws[3][0];
  ss = ws[0][1] + ws[1][1] + ws[2][1] + ws[3][1];
  float mu = s * (1.0f / D_);
  float var = ss * (1.0f / D_) - mu * mu;
  float rs = rsqrtf(var + EPS_);
  f32x4 gg = *(const f32x4*)(g + t * 4);
  f32x4 bb = *(const f32x4*)(bv + t * 4);
  f32x4 o4;
#pragma unroll
  for (int i = 0; i < 4; i++) o4[i] = (v[i] - mu) * rs * gg[i] + bb[i];
  *(f32x4*)(out + (size_t)row * D_ + t * 4) = o4;
}

// ---- weight prep: fp32 -> bf16 (job 1 transposes). z=5: text LayerNorm. ---
__global__ __launch_bounds__(256) void k_wprep(
    const float* __restrict__ w0, const float* __restrict__ w1,
    const float* __restrict__ w2, const float* __restrict__ w3,
    const float* __restrict__ w4, __bf16* __restrict__ o0,
    __bf16* __restrict__ o1, __bf16* __restrict__ o2,
    __bf16* __restrict__ o3, __bf16* __restrict__ o4p,
    const float* __restrict__ text, const float* __restrict__ g1,
    const float* __restrict__ b1, __bf16* __restrict__ Yh,
    __bf16* __restrict__ Yl) {
  int z = blockIdx.z;
  int t = threadIdx.x;
  if (z == 5) {
    // ---- fused text LayerNorm (1024 blocks in z-slice, 512 used) ----
    int row = blockIdx.y * 32 + blockIdx.x;
    if (row >= B_) return;
    f32x4 xv = *(const f32x4*)(text + (size_t)row * D_ + t * 4);
    float s = xv[0] + xv[1] + xv[2] + xv[3];
    float ss = xv[0]*xv[0] + xv[1]*xv[1] + xv[2]*xv[2] + xv[3]*xv[3];
#pragma unroll
    for (int o = 32; o > 0; o >>= 1) { s += __shfl_xor(s, o); ss += __shfl_xor(ss, o); }
    __shared__ float ws[4][2];
    int w = t >> 6;
    if ((t & 63) == 0) { ws[w][0] = s; ws[w][1] = ss; }
    __syncthreads();
    s = ws[0][0] + ws[1][0] + ws[2][0] + ws[3][0];
    ss = ws[0][1] + ws[1][1] + ws[2][1] + ws[3][1];
    float mu = s * (1.0f / D_);
    float var = ss * (1.0f / D_) - mu * mu;
    float rs = rsqrtf(var + EPS_);
    f32x4 gg = *(const f32x4*)(g1 + t * 4);
    f32x4 bb = *(const f32x4*)(b1 + t * 4);
    bf16x4 h4, l4;
#pragma unroll
    for (int i = 0; i < 4; i++) {
      float o = (xv[i] - mu) * rs * gg[i] + bb[i];
      h4[i] = (__bf16)o;
      l4[i] = (__bf16)(o - (float)h4[i]);
    }
    *(bf16x4*)(Yh + (size_t)row * D_ + t * 4) = h4;
    *(bf16x4*)(Yl + (size_t)row * D_ + t * 4) = l4;
    return;
  }
  const float* src = (z == 0) ? w0 : (z == 1) ? w1 : (z == 2) ? w2 : (z == 3) ? w3 : w4;
  __bf16* dst = (z == 0) ? o0 : (z == 1) ? o1 : (z == 2) ? o2 : (z == 3) ? o3 : o4p;
  if (z != 1) {
    int row = blockIdx.y * 32 + (t >> 3);
    int col = blockIdx.x * 32 + (t & 7) * 4;
    f32x4 v = *(const f32x4*)(src + (size_t)row * D_ + col);
    bf16x4 o;
    o[0] = (__bf16)v[0]; o[1] = (__bf16)v[1]; o[2] = (__bf16)v[2]; o[3] = (__bf16)v[3];
    *(bf16x4*)(dst + (size_t)row * D_ + col) = o;
  } else {
    __shared__ float tile[32][33];
    int ti = blockIdx.y, tj = blockIdx.x;
    int c = t & 31, r0 = t >> 5;
#pragma unroll
    for (int i = 0; i < 4; i++) {
      int r = r0 + i * 8;
      tile[r][c] = src[(size_t)(ti * 32 + r) * D_ + tj * 32 + c];
    }
    __syncthreads();
#pragma unroll
    for (int i = 0; i < 4; i++) {
      int r = r0 + i * 8;
      dst[(size_t)(tj * 32 + r) * D_ + ti * 32 + c] = (__bf16)tile[c][r];
    }
  }
}

// ---- GEMM: C[M,N] = (Ah+Al)[M,K] @ W[N,K]^T + bias. 32x32 tile per block. --
// Split-K x8: 512 threads = 8 waves, wave w owns K-slice [w*K/8, (w+1)*K/8).
// Frag layout: A/B row = lane&15, k = (lane>>4)*8+j ; C/D col = lane&15, row = quad*4+reg
template <int OUT>
__global__ __launch_bounds__(512) void k_gemm32(
    const __bf16* __restrict__ Ah, const __bf16* __restrict__ Al,
    const __bf16* __restrict__ W, const float* __restrict__ bias,
    float* __restrict__ Cf, __bf16* __restrict__ Ch, __bf16* __restrict__ Cl,
    int N, int K) {
  int t = threadIdx.x;
  int lane = t & 63, wv = t >> 6;      // 8 waves
  int r = lane & 15, quad = lane >> 4;
  int tn = blockIdx.x, tm = blockIdx.y;
  int kw = K >> 3;                     // 128 per wave
  const __bf16* pah0 = Ah + (size_t)(tm * 32 + r) * K + wv * kw + quad * 8;
  const __bf16* pah1 = pah0 + (size_t)16 * K;
  const __bf16* pal0 = Al + (size_t)(tm * 32 + r) * K + wv * kw + quad * 8;
  const __bf16* pal1 = pal0 + (size_t)16 * K;
  const __bf16* pw0 = W + (size_t)(tn * 32 + r) * K + wv * kw + quad * 8;
  const __bf16* pw1 = pw0 + (size_t)16 * K;
  f32x4 acc00 = {0,0,0,0}, acc01 = {0,0,0,0}, acc10 = {0,0,0,0}, acc11 = {0,0,0,0};
  bf16x8 ah0 = *(const bf16x8*)pah0, ah1 = *(const bf16x8*)pah1;
  bf16x8 al0 = *(const bf16x8*)pal0, al1 = *(const bf16x8*)pal1;
  bf16x8 w0v = *(const bf16x8*)pw0, w1v = *(const bf16x8*)pw1;
  for (int k0 = 0; k0 < kw; k0 += 32) {
    int kn = (k0 + 32 < kw) ? (k0 + 32) : 0;  // dummy refetch on last iter
    bf16x8 nah0 = *(const bf16x8*)(pah0 + kn);
    bf16x8 nah1 = *(const bf16x8*)(pah1 + kn);
    bf16x8 nal0 = *(const bf16x8*)(pal0 + kn);
    bf16x8 nal1 = *(const bf16x8*)(pal1 + kn);
    bf16x8 nw0 = *(const bf16x8*)(pw0 + kn);
    bf16x8 nw1 = *(const bf16x8*)(pw1 + kn);
    acc00 = __builtin_amdgcn_mfma_f32_16x16x32_bf16(ah0, w0v, acc00, 0, 0, 0);
    acc01 = __builtin_amdgcn_mfma_f32_16x16x32_bf16(ah0, w1v, acc01, 0, 0, 0);
    acc10 = __builtin_amdgcn_mfma_f32_16x16x32_bf16(ah1, w0v, acc10, 0, 0, 0);
    acc11 = __builtin_amdgcn_mfma_f32_16x16x32_bf16(ah1, w1v, acc11, 0, 0, 0);
    acc00 = __builtin_amdgcn_mfma_f32_16x16x32_bf16(al0, w0v, acc00, 0, 0, 0);
    acc01 = __builtin_amdgcn_mfma_f32_16x16x32_bf16(al0, w1v, acc01, 0, 0, 0);
    acc10 = __builtin_amdgcn_mfma_f32_16x16x32_bf16(al1, w0v, acc10, 0, 0, 0);
    acc11 = __builtin_amdgcn_mfma_f32_16x16x32_bf16(al1, w1v, acc11, 0, 0, 0);
    ah0 = nah0; ah1 = nah1; al0 = nal0; al1 = nal1; w0v = nw0; w1v = nw1;
  }
  // ---- cross-wave split-K reduction via LDS (pad 17 -> conflict-light) ----
  __shared__ float red[8][64][17];
  *(f32x4*)(&red[wv][lane][0])  = acc00;
  *(f32x4*)(&red[wv][lane][4])  = acc01;
  *(f32x4*)(&red[wv][lane][8])  = acc10;
  *(f32x4*)(&red[wv][lane][12]) = acc11;
  __syncthreads();
  // 1024 outputs, 512 threads -> 2 each. j in [0,16): a=j>>2 (acc), i=j&3.
  int re = lane & 15, qe = lane >> 4;
#pragma unroll
  for (int u = 0; u < 2; u++) {
    int j = (t >> 6) * 2 + u;
    int a = j >> 2, i = j & 3;
    float val = 0.0f;
#pragma unroll
    for (int ww = 0; ww < 8; ww++) val += red[ww][lane][j];
    int row = tm * 32 + qe * 4 + i + ((a >> 1) << 4);
    int col = tn * 32 + re + ((a & 1) << 4);
    if (bias) val += bias[col];
    size_t o = (size_t)row * N + col;
    if (OUT == 0) {
      Cf[o] = val;
    } else {
      __bf16 h = (__bf16)val;
      Ch[o] = h;
      Cl[o] = (__bf16)(val - (float)h);
    }
  }
}

// ---------------- fused flash-style attention over video -------------------
// One block (16 waves) per b. Wave w owns rows [w*8, w*8+8); per-lane cols
// lane*4 + i*256. Per-b prep (sum_gq, dot_bq, qkb, gq) fused into the
// prologue as per-wave shuffle reductions. PV accumulator stays column-local
// in registers -> NO barriers in the main loop. Per-wave online softmax
// (m,S,C,O); single flash-merge at the end.
__global__ __launch_bounds__(1024) void k_attn(
    const float* __restrict__ video, const float* __restrict__ q2,
    const __bf16* __restrict__ qh, const __bf16* __restrict__ ql,
    const float* __restrict__ g, const float* __restrict__ bv,
    const float* __restrict__ kb, __bf16* __restrict__ ctxh,
    __bf16* __restrict__ ctxl) {
  __shared__ float Xc[16][1032];     // per-wave scaled O partials (padded)
  __shared__ float mSC[16][4];       // m_w, S_w, C_w per wave
  int b = blockIdx.x, t = threadIdx.x;
  int w = t >> 6, lane = t & 63;
  // issue first video frame loads immediately (critical HBM path)
  const float* vbase = video + ((size_t)b * F_ + w * 8) * D_ + lane * 4;
  f32x4 vA[4], vB[4];
#pragma unroll
  for (int i = 0; i < 4; i++) vA[i] = *(const f32x4*)(vbase + i * 256);
  // ---- fused per-b prep: gq (regs), sum_gq, dot_bq, qkb (wave reduce) ----
  const float* q2p = q2 + (size_t)b * D_ + lane * 4;
  const float* gp = g + lane * 4;
  const float* bp = bv + lane * 4;
  const float* kp = kb + lane * 4;
  const __bf16* qhp = qh + (size_t)b * D_ + lane * 4;
  const __bf16* qlp = ql + (size_t)b * D_ + lane * 4;
  f32x4 gqr[4];
  float s1 = 0.f, s2 = 0.f, s3 = 0.f;
#pragma unroll
  for (int i = 0; i < 4; i++) {
    f32x4 qv = *(const f32x4*)(q2p + i * 256);
    f32x4 g4 = *(const f32x4*)(gp + i * 256);
    f32x4 b4 = *(const f32x4*)(bp + i * 256);
    f32x4 k4 = *(const f32x4*)(kp + i * 256);
    bf16x4 h4 = *(const bf16x4*)(qhp + i * 256);
    bf16x4 l4 = *(const bf16x4*)(qlp + i * 256);
#pragma unroll
    for (int j = 0; j < 4; j++) {
      float gq = g4[j] * qv[j];
      gqr[i][j] = gq;
      s1 += gq;
      s2 += b4[j] * qv[j];
      s3 += k4[j] * ((float)h4[j] + (float)l4[j]);
    }
  }
#pragma unroll
  for (int o = 32; o > 0; o >>= 1) {
    s1 += __shfl_xor(s1, o); s2 += __shfl_xor(s2, o); s3 += __shfl_xor(s3, o);
  }
  float sgq = s1, dbq = s2, qk = s3;
  f32x4 O[4];
#pragma unroll
  for (int i = 0; i < 4; i++) O[i] = (f32x4){0.f, 0.f, 0.f, 0.f};
  float m_run = -1e30f, S = 0.0f, Cc = 0.0f;
  for (int f = 0; f < 8; f++) {
    if (f < 7) {
      const float* nb = vbase + (size_t)(f + 1) * D_;
#pragma unroll
      for (int i = 0; i < 4; i++) vB[i] = *(const f32x4*)(nb + i * 256);
    }
    float sx = 0.f, sxx = 0.f, sxg = 0.f;
#pragma unroll
    for (int i = 0; i < 4; i++) {
      f32x4 v = vA[i], gg = gqr[i];
#pragma unroll
      for (int j = 0; j < 4; j++) {
        sx += v[j];
        sxx += v[j] * v[j];
        sxg += v[j] * gg[j];
      }
    }
#pragma unroll
    for (int o = 16; o > 0; o >>= 1) {
      sx += __shfl_xor(sx, o);
      sxx += __shfl_xor(sxx, o);
      sxg += __shfl_xor(sxg, o);
    }
    sx += __shfl_xor(sx, 32);
    sxx += __shfl_xor(sxx, 32);
    sxg += __shfl_xor(sxg, 32);
    float mu = sx * (1.0f / D_);
    float var = sxx * (1.0f / D_) - mu * mu;
    float rs = rsqrtf(var + EPS_);
    float l = (rs * (sxg - mu * sgq) + dbq + qk) * 0.03125f;
    float m_new = fmaxf(m_run, l);
    float alpha = __expf(m_run - m_new);
    float e = __expf(l - m_new);
    float af = e * rs;
    S = S * alpha + e;
    Cc = Cc * alpha + af * mu;
#pragma unroll
    for (int i = 0; i < 4; i++) {
#pragma unroll
      for (int j = 0; j < 4; j++) O[i][j] = O[i][j] * alpha + af * vA[i][j];
    }
    m_run = m_new;
#pragma unroll
    for (int i = 0; i < 4; i++) vA[i] = vB[i];
  }
  // ---- flash merge of 16 per-wave states ----
  if (lane == 0) { mSC[w][0] = m_run; mSC[w][1] = S; mSC[w][2] = Cc; }
  __syncthreads();
  float mstar = -1e30f;
#pragma unroll
  for (int i = 0; i < 16; i++) mstar = fmaxf(mstar, mSC[i][0]);
  float myscale = __expf(m_run - mstar);
#pragma unroll
  for (int i = 0; i < 4; i++) {
    f32x4 o4;
#pragma unroll
    for (int j = 0; j < 4; j++) o4[j] = O[i][j] * myscale;
    *(f32x4*)(&Xc[w][lane * 4 + i * 256]) = o4;
  }
  float Sstar = 0.f, Cstar = 0.f;
#pragma unroll
  for (int i = 0; i < 16; i++) {
    float e = __expf(mSC[i][0] - mstar);
    Sstar += mSC[i][1] * e;
    Cstar += mSC[i][2] * e;
  }
  __syncthreads();
  float Osum = 0.f;
#pragma unroll
  for (int i = 0; i < 16; i++) Osum += Xc[i][t];
  float inv = 1.0f / Sstar;
  float v = g[t] * ((Osum - Cstar) * inv) + bv[t];
  __bf16 h = (__bf16)v;
  ctxh[(size_t)b * D_ + t] = h;
  ctxl[(size_t)b * D_ + t] = (__bf16)(v - (float)h);
}

extern "C" void kernel_launch(void* const* d_in, const int* in_sizes, int n_in,
                              void* d_out, int out_size, void* d_ws, size_t ws_size,
                              hipStream_t stream) {
  (void)in_sizes; (void)n_in; (void)out_size; (void)ws_size;
  const float* text = (const float*)d_in[0];
  const float* video = (const float*)d_in[1];
  const float* q_w = (const float*)d_in[2];
  const float* k_w = (const float*)d_in[3];
  const float* v_w = (const float*)d_in[4];
  const float* out_w = (const float*)d_in[5];
  const float* lin_w = (const float*)d_in[6];
  const float* q_b = (const float*)d_in[7];
  const float* k_b = (const float*)d_in[8];
  const float* v_b = (const float*)d_in[9];
  const float* out_b = (const float*)d_in[10];
  const float* lin_b = (const float*)d_in[11];
  const float* ln1_g = (const float*)d_in[12];
  const float* ln1_b = (const float*)d_in[13];
  const float* ln2_g = (const float*)d_in[14];
  const float* ln2_b = (const float*)d_in[15];
  const float* ln3_g = (const float*)d_in[16];
  const float* ln3_b = (const float*)d_in[17];
  float* out = (float*)d_out;

  const size_t BD = (size_t)B_ * D_;   // 524288
  const size_t DD = (size_t)D_ * D_;   // 1048576
  float* f = (float*)d_ws;
  float* slotF1 = f;            // BD fp32 (q2, attn2)
  float* slotF2 = f + BD;       // BD fp32 (lin)
  float* scratch = f + 2 * BD;
  __bf16* P1h = (__bf16*)(scratch + 4 * B_);  // plane pair 1 (t_ln, ctx)
  __bf16* P1l = P1h + BD;
  __bf16* P2h = P1h + 2 * BD;                 // plane pair 2 (qv, attn1)
  __bf16* P2l = P1h + 3 * BD;
  __bf16* P3h = P1h + 4 * BD;                 // plane pair 3 (attno)
  __bf16* P3l = P1h + 5 * BD;
  __bf16* Wq = P1h + 6 * BD;
  __bf16* WkT = Wq + DD;
  __bf16* Wv = Wq + 2 * DD;
  __bf16* Wo = Wq + 3 * DD;
  __bf16* Wl = Wq + 4 * DD;
  // total ws use: ~24.5 MB

  dim3 gemm_grid(D_ / 32, B_ / 32);  // (32, 16)

  // weights -> bf16 (+ k_w transpose) and text LayerNorm, one dispatch
  k_wprep<<<dim3(32, 32, 6), 256, 0, stream>>>(q_w, k_w, v_w, out_w, lin_w,
                                               Wq, WkT, Wv, Wo, Wl,
                                               text, ln1_g, ln1_b, P1h, P1l);
  // q path
  k_gemm32<1><<<gemm_grid, 512, 0, stream>>>(P1h, P1l, Wq, q_b, nullptr, P2h, P2l, D_, D_);   // qv
  k_gemm32<0><<<gemm_grid, 512, 0, stream>>>(P2h, P2l, WkT, nullptr, slotF1, nullptr, nullptr, D_, D_); // q2
  // fused attention (prep_q folded in): video read once; ctx -> P1 planes
  k_attn<<<B_, 1024, 0, stream>>>(video, slotF1, P2h, P2l,
                                  ln1_g, ln1_b, k_b, P1h, P1l);
  // output projections + norms
  k_gemm32<1><<<gemm_grid, 512, 0, stream>>>(P1h, P1l, Wv, v_b, nullptr, P2h, P2l, D_, D_);   // attn1
  k_gemm32<0><<<gemm_grid, 512, 0, stream>>>(P2h, P2l, Wo, out_b, slotF1, nullptr, nullptr, D_, D_); // attn2
  k_ln<1><<<B_, 256, 0, stream>>>(slotF1, ln2_g, ln2_b, nullptr, P3h, P3l);    // attno
  k_gemm32<0><<<gemm_grid, 512, 0, stream>>>(P3h, P3l, Wl, lin_b, slotF2, nullptr, nullptr, D_, D_); // lin
  k_final<<<B_, 256, 0, stream>>>(P3h, P3l, slotF2, ln3_g, ln3_b, out);
}